// Round 17
// baseline (65.908 us; speedup 1.0000x reference)
//
#include <hip/hip_runtime.h>
#include <math.h>

static constexpr int Bn = 32768;

// ws layout (floats)
#define WS_G     1792     // [8][8]
#define WS_g     1856     // [8]
#define WS_BW    1864     // [24]  b_w[k*3+m]
#define WS_Q00   1888
#define WS_WSUM  1889
#define WS_CB8   2048     // [8][260] : per sub(=k) {per n: w, cb[3]} stride 260 (bank-disjoint)

__host__ __device__ constexpr int tidx(int i, int j) { return i*10 - i*(i+1)/2 + j; } // i<=j (upper packed, 10x10)
__host__ __device__ constexpr int lidx(int i, int j) { return i*(i+1)/2 + j; }        // i>=j (lower packed)

// ---------------- K1: precompute (1 block, 64 threads; GJ parallelized in LDS) ----------------
__global__ void k_pre(const float* __restrict__ bb, const float* __restrict__ w,
                      const float* __restrict__ lam, float* __restrict__ ws)
{
  __shared__ float s_w[64], s_sw[64], s_bw[24], s_barb[64][24];
  __shared__ float s_BtB[64];
  __shared__ float s_M[8][16];      // [A | Iv]
  __shared__ float s_u[8], s_g[8], s_red[64], s_wsum, s_s;
  const int t = threadIdx.x;
  const int i8 = t >> 3, j8 = t & 7;
  const float lv = lam[0];

  s_w[t]  = w[t];
  s_sw[t] = sqrtf(fmaxf(s_w[t], 0.0f));
  __syncthreads();
  if (t == 0) { float a = 0; for (int n = 0; n < 64; n++) a += s_w[n]; s_wsum = a; }
  __syncthreads();
  const float wsum = s_wsum;
  if (t < 24) {
    float a = 0;
    for (int n = 0; n < 64; n++) a += bb[t*64 + n] * s_w[n];
    s_bw[t] = a / wsum;
  }
  __syncthreads();
  for (int km = 0; km < 24; ++km)
    s_barb[t][km] = s_sw[t] * (bb[km*64 + t] - s_bw[km]);
  __syncthreads();
  {
    float a = 0;
    for (int n = 0; n < 64; n++)
      for (int j = 0; j < 3; j++)
        a += s_barb[n][i8*3 + j] * s_barb[n][j8*3 + j];
    s_BtB[t] = a;
  }
  __syncthreads();
  s_M[i8][j8]     = 2.0f * (s_BtB[t] + ((i8 == j8) ? lv : 0.0f));
  s_M[i8][8 + j8] = (i8 == j8) ? 1.0f : 0.0f;
#pragma unroll
  for (int k = 0; k < 8; k++) {
    __syncthreads();
    const float fk  = s_M[i8][k];
    const float piv = 1.0f / s_M[k][k];
    __syncthreads();
    if (i8 == k) { s_M[k][j8] *= piv; s_M[k][8 + j8] *= piv; }
    __syncthreads();
    if (i8 != k) {
      s_M[i8][j8]     -= fk * s_M[k][j8];
      s_M[i8][8 + j8] -= fk * s_M[k][8 + j8];
    }
  }
  __syncthreads();
  if (t < 8) {
    float a = 0;
#pragma unroll
    for (int j = 0; j < 8; j++) a += s_M[t][8 + j];
    s_u[t] = a;
  }
  __syncthreads();
  if (t == 0) {
    float s = 0;
#pragma unroll
    for (int j = 0; j < 8; j++) s += s_u[j];
    s_s = s;
  }
  __syncthreads();
  const float s = s_s;
  if (t < 8) s_g[t] = s_u[t] / s;
  const float Gel = s_M[i8][8 + j8] - s_u[i8] * s_u[j8] / s;
  ws[WS_G + t] = Gel;
  __syncthreads();
  s_red[t] = s_g[i8] * (s_BtB[t] + ((i8 == j8) ? lv : 0.0f)) * s_g[j8];
  __syncthreads();
  if (t == 0) {
    float a = 0;
    for (int n = 0; n < 64; n++) a += s_red[n];
    ws[WS_Q00]  = a;
    ws[WS_WSUM] = wsum;
  }
  if (t < 8)  ws[WS_g + t]  = s_g[t];
  if (t < 24) ws[WS_BW + t] = s_bw[t];
  {                                     // per-sub(=k) packed table, t = n
#pragma unroll
    for (int sub = 0; sub < 8; sub++) {
      float* p = ws + WS_CB8 + sub*260 + t*4;
      p[0] = s_w[t];
#pragma unroll
      for (int kk = 0; kk < 3; kk++)
        p[1 + kk] = s_sw[t] * s_barb[t][sub*3 + kk];
    }
  }
}

// ---------------- K2: fused build + tridiag + 9-way Sturm + Cholesky inverse-iteration ----------------
// 512 threads = 64 batches x 8 subs (sub owns k = sub). launch_bounds(512,2): VGPR budget 256.
__global__ __launch_bounds__(512, 2) void k_main(const float* __restrict__ y,
                                                 const float* __restrict__ ws,
                                                 float* __restrict__ out)
{
  __shared__ float s_cb[8*260];
  __shared__ float s_G[64], s_g8[8], s_bw[24];
  __shared__ float s_F[72][66];     // [(k*3+j)*3+m][lb]
  __shared__ float s_Q[55][66];
  const int t   = threadIdx.x;
  const int lb  = t >> 3;           // local batch 0..63
  const int sub = t & 7;            // owns k = sub
  const int b   = blockIdx.x * 64 + lb;

  for (int i = t; i < 8*260; i += 512) s_cb[i] = ws[WS_CB8 + i];
  if (t < 64) s_G[t]  = ws[WS_G + t];
  if (t < 8)  s_g8[t] = ws[WS_g + t];
  if (t >= 8 && t < 32) s_bw[t - 8] = ws[WS_BW + (t - 8)];
  const float q00v = ws[WS_Q00];
  const float wsum = ws[WS_WSUM];
  __syncthreads();

  // ---- build phase ----
  const float* yb = y + (size_t)b * 192;
  float F3[3][3];
  float gw[6];
  float ywa[3] = {0, 0, 0};
#pragma unroll
  for (int i = 0; i < 3; i++) { F3[i][0] = 0; F3[i][1] = 0; F3[i][2] = 0; }
#pragma unroll
  for (int i = 0; i < 6; i++) gw[i] = 0;

  const float4* cbp = reinterpret_cast<const float4*>(s_cb + sub*260);
  for (int n4 = 0; n4 < 16; n4++) {
    float4 v0 = reinterpret_cast<const float4*>(yb)[n4];
    float4 v1 = reinterpret_cast<const float4*>(yb + 64)[n4];
    float4 v2 = reinterpret_cast<const float4*>(yb + 128)[n4];
    float a0[4] = {v0.x, v0.y, v0.z, v0.w};
    float a1[4] = {v1.x, v1.y, v1.z, v1.w};
    float a2[4] = {v2.x, v2.y, v2.z, v2.w};
#pragma unroll
    for (int l = 0; l < 4; l++) {
      const int n = 4*n4 + l;
      float4 va = cbp[n];
      const float cb3[3] = {va.y, va.z, va.w};
      float ym0 = a0[l], ym1 = a1[l], ym2 = a2[l];
      float wn  = va.x;
      float wy0 = wn*ym0, wy1 = wn*ym1, wy2 = wn*ym2;
      ywa[0] += wy0; ywa[1] += wy1; ywa[2] += wy2;      // redundant x8 (cheap)
      gw[0] += wy0*ym0; gw[1] += wy0*ym1; gw[2] += wy0*ym2;
      gw[3] += wy1*ym1; gw[4] += wy1*ym2; gw[5] += wy2*ym2;
#pragma unroll
      for (int kk = 0; kk < 3; kk++) {
        F3[kk][0] += cb3[kk]*ym0; F3[kk][1] += cb3[kk]*ym1; F3[kk][2] += cb3[kk]*ym2;
      }
    }
  }
  const float iws = 1.0f / wsum;
  float yw[3] = {ywa[0]*iws, ywa[1]*iws, ywa[2]*iws};
  float Gram[6];
  Gram[0] = gw[0] - ywa[0]*ywa[0]*iws;
  Gram[1] = gw[1] - ywa[0]*ywa[1]*iws;
  Gram[2] = gw[2] - ywa[0]*ywa[2]*iws;
  Gram[3] = gw[3] - ywa[1]*ywa[1]*iws;
  Gram[4] = gw[4] - ywa[1]*ywa[2]*iws;
  Gram[5] = gw[5] - ywa[2]*ywa[2]*iws;

#pragma unroll
  for (int kk = 0; kk < 3; kk++)
#pragma unroll
    for (int m = 0; m < 3; m++)
      s_F[(sub*3 + kk)*3 + m][lb] = F3[kk][m];
  if (sub == 0) s_Q[0][lb] = q00v;
  {
    const float g0 = s_g8[sub];
#pragma unroll
    for (int e = 0; e < 9; e++) {
      const int j = e / 3, m = e % 3;
      float p = g0 * F3[j][m];
      p += __shfl_xor(p, 1);
      p += __shfl_xor(p, 2);
      p += __shfl_xor(p, 4);
      if ((e & 7) == sub) s_Q[tidx(0, 1 + e)][lb] = -p;
    }
  }
  __syncthreads();

  // FG row for my k2 = sub (kept in regs)
  float FGr[9];
  {
    float gcol[8];
#pragma unroll
    for (int k = 0; k < 8; k++) gcol[k] = s_G[k*8 + sub];
#pragma unroll
    for (int e = 0; e < 9; e++) {
      const int j = e / 3, m = e % 3;
      float a = 0;
#pragma unroll
      for (int k = 0; k < 8; k++) a += gcol[k] * s_F[(k*3 + j)*3 + m][lb];
      FGr[e] = a;
    }
  }
#pragma unroll
  for (int e = 0; e < 9; e++)
#pragma unroll
    for (int f = e; f < 9; f++) {
      const int j = e/3, m = e%3, j2 = f/3, m2 = f%3;
      float p = FGr[e] * F3[j2][m2];
      p += __shfl_xor(p, 1);
      p += __shfl_xor(p, 2);
      p += __shfl_xor(p, 4);
      if ((tidx(1 + e, 1 + f) & 7) == sub) {
        const float gterm = (j == j2) ? Gram[(m <= m2) ? (m*3 - m*(m+1)/2 + m2) : (m2*3 - m2*(m2+1)/2 + m)] : 0.0f;
        s_Q[tidx(1 + e, 1 + f)][lb] = -2.0f*p + gterm;
      }
    }
  __syncthreads();

  // ---- tridiagonalize Q (register copy) via Householder: T = (ad[10], b2[9]) ----
  float Mm[55];
#pragma unroll
  for (int i = 0; i < 10; i++)
#pragma unroll
    for (int j = 0; j <= i; j++)
      Mm[lidx(i,j)] = s_Q[tidx(j,i)][lb];

  float ad[10], b2[9];
#pragma unroll
  for (int j = 0; j < 8; j++) {
    float s2 = 0;
#pragma unroll
    for (int i = j + 1; i < 10; i++) s2 += Mm[lidx(i,j)] * Mm[lidx(i,j)];
    const float x0 = Mm[lidx(j+1,j)];
    const float anorm = __builtin_amdgcn_sqrtf(s2);
    const float alpha = (x0 > 0.0f) ? -anorm : anorm;
    const float uu = s2 - alpha * x0;
    const float beta = (uu > 1e-35f) ? __builtin_amdgcn_rcpf(uu) : 0.0f;
    float u[10], p[10];
    u[j+1] = x0 - alpha;
#pragma unroll
    for (int i = j + 2; i < 10; i++) u[i] = Mm[lidx(i,j)];
#pragma unroll
    for (int i = j + 1; i < 10; i++) {
      float acc = 0;
#pragma unroll
      for (int k = j + 1; k < 10; k++) acc += Mm[(i >= k) ? lidx(i,k) : lidx(k,i)] * u[k];
      p[i] = beta * acc;
    }
    float K = 0;
#pragma unroll
    for (int i = j + 1; i < 10; i++) K += u[i] * p[i];
    K *= 0.5f * beta;
#pragma unroll
    for (int i = j + 1; i < 10; i++) p[i] -= K * u[i];
#pragma unroll
    for (int i = j + 1; i < 10; i++)
#pragma unroll
      for (int k = j + 1; k <= i; k++)
        Mm[lidx(i,k)] -= u[i]*p[k] + p[i]*u[k];
    ad[j] = Mm[lidx(j,j)];
    b2[j] = s2;
  }
  ad[8] = Mm[lidx(8,8)];
  ad[9] = Mm[lidx(9,9)];
  b2[8] = Mm[lidx(9,8)] * Mm[lidx(9,8)];

  float b2max = b2[0];
#pragma unroll
  for (int i = 1; i < 9; i++) b2max = fmaxf(b2max, b2[i]);
  const float pm = 1e-20f * b2max + 1e-30f;

  // ---- phase A: 9-way Sturm bisection on T (8 probes/round, 7 rounds ~ 22.2 bits) ----
  float lo = 0.0f, hi = s_Q[0][lb];
#pragma unroll
  for (int j = 1; j < 10; j++) hi = fminf(hi, s_Q[tidx(j,j)][lb]);

  const int base = (t & 63) & ~7;
  const float ninth = 1.0f / 9.0f;
  for (int round = 0; round < 7; ++round) {
    const float h9 = ninth * (hi - lo);
    const float mid = lo + (float)(sub + 1) * h9;
    int neg = 0;
    float d = ad[0] - mid;
    neg += (d < 0.0f) ? 1 : 0;
#pragma unroll
    for (int i = 1; i < 10; i++) {
      d = (fabsf(d) < pm) ? -pm : d;
      d = ad[i] - mid - b2[i-1] * __builtin_amdgcn_rcpf(d);
      neg += (d < 0.0f) ? 1 : 0;
    }
    int j = 0;                       // inertia monotone => max prefix of zero-neg probes
    j = (__shfl(neg, base + 0) == 0) ? 1 : j;
    j = (__shfl(neg, base + 1) == 0) ? 2 : j;
    j = (__shfl(neg, base + 2) == 0) ? 3 : j;
    j = (__shfl(neg, base + 3) == 0) ? 4 : j;
    j = (__shfl(neg, base + 4) == 0) ? 5 : j;
    j = (__shfl(neg, base + 5) == 0) ? 6 : j;
    j = (__shfl(neg, base + 6) == 0) ? 7 : j;
    j = (__shfl(neg, base + 7) == 0) ? 8 : j;
    const float nlo = lo + (float)j * h9;
    const float nhi = lo + (float)(j + 1) * h9;
    lo = nlo; hi = nhi;
  }

  // ---- phase B: Cholesky of (Q - sigma I) + 3 inverse iterations (redundant x8) ----
  float M[55], id[10];
#pragma unroll
  for (int i = 0; i < 10; i++)
#pragma unroll
    for (int j = 0; j <= i; j++)
      M[lidx(i,j)] = s_Q[tidx(j,i)][lb];
  float tr = 0.0f;
#pragma unroll
  for (int i = 0; i < 10; i++) tr += M[lidx(i,i)];
  const float delta = 1e-5f * fabsf(tr) + 1e-30f;
  const float sigma = lo - delta;
#pragma unroll
  for (int i = 0; i < 10; i++) M[lidx(i,i)] -= sigma;

#pragma unroll
  for (int j = 0; j < 10; j++) {
    float d = M[lidx(j,j)];
#pragma unroll
    for (int t2 = 0; t2 < j; t2++) d -= M[lidx(j,t2)] * M[lidx(j,t2)];
    d = fmaxf(d, 1e-30f);
    float is = __builtin_amdgcn_rsqf(d);
    id[j] = is;
#pragma unroll
    for (int i = j + 1; i < 10; i++) {
      float a = M[lidx(i,j)];
#pragma unroll
      for (int t2 = 0; t2 < j; t2++) a -= M[lidx(i,t2)] * M[lidx(j,t2)];
      M[lidx(i,j)] = a * is;
    }
  }

  float x[10];
#pragma unroll
  for (int i = 0; i < 10; i++) x[i] = 1.0f;
#pragma unroll
  for (int it = 0; it < 3; ++it) {
#pragma unroll
    for (int i = 0; i < 10; i++) {
      float a = x[i];
#pragma unroll
      for (int j = 0; j < i; j++) a -= M[lidx(i,j)] * x[j];
      x[i] = a * id[i];
    }
#pragma unroll
    for (int i = 9; i >= 0; i--) {
      float a = x[i];
#pragma unroll
      for (int j = i + 1; j < 10; j++) a -= M[lidx(j,i)] * x[j];
      x[i] = a * id[i];
    }
    float s2 = 0;
#pragma unroll
    for (int i = 0; i < 10; i++) s2 += x[i]*x[i];
    float sc = __builtin_amdgcn_rsqf(s2 + 1e-38f);
#pragma unroll
    for (int i = 0; i < 10; i++) x[i] *= sc;
  }

  // ---- epilogue: R, c, t ----
  const float inv0 = __builtin_amdgcn_rcpf(x[0]);
  float R[3][3];
#pragma unroll
  for (int r = 0; r < 3; r++)
#pragma unroll
    for (int cc = 0; cc < 3; cc++)
      R[r][cc] = x[1 + 3*cc + r] * inv0;

  float cv;
  {
    float a = 0;
#pragma unroll
    for (int e = 0; e < 9; e++) a += x[1 + e] * FGr[e];
    cv = 2.0f * inv0 * a + s_g8[sub];
    out[(size_t)12*Bn + (size_t)b*8 + sub] = cv;
  }
  float um0 = s_bw[sub*3 + 0] * cv;
  float um1 = s_bw[sub*3 + 1] * cv;
  float um2 = s_bw[sub*3 + 2] * cv;
  um0 += __shfl_xor(um0, 1); um0 += __shfl_xor(um0, 2); um0 += __shfl_xor(um0, 4);
  um1 += __shfl_xor(um1, 1); um1 += __shfl_xor(um1, 2); um1 += __shfl_xor(um1, 4);
  um2 += __shfl_xor(um2, 1); um2 += __shfl_xor(um2, 2); um2 += __shfl_xor(um2, 4);

#pragma unroll
  for (int r = 0; r < 3; r++)
#pragma unroll
    for (int cc = 0; cc < 3; cc++)
      if (((r*3 + cc) & 7) == sub)
        out[(size_t)b*9 + r*3 + cc] = R[r][cc];
  if (sub == 1) {
#pragma unroll
    for (int r = 0; r < 3; r++)
      out[(size_t)9*Bn + (size_t)b*3 + r] = yw[r] - (R[r][0]*um0 + R[r][1]*um1 + R[r][2]*um2);
  }
}

extern "C" void kernel_launch(void* const* d_in, const int* in_sizes, int n_in,
                              void* d_out, int out_size, void* d_ws, size_t ws_size,
                              hipStream_t stream) {
  const float* y   = (const float*)d_in[0];
  const float* bb  = (const float*)d_in[1];
  const float* w   = (const float*)d_in[2];
  const float* lam = (const float*)d_in[3];
  float* ws  = (float*)d_ws;
  float* out = (float*)d_out;
  k_pre <<<1,      64, 0, stream>>>(bb, w, lam, ws);
  k_main<<<Bn/64, 512, 0, stream>>>(y, ws, out);
}

// Round 18
// 42.805 us; speedup vs baseline: 1.5397x; 1.5397x over previous
//
#include <hip/hip_runtime.h>
#include <math.h>

static constexpr int Bn = 32768;

// ws layout (floats)
#define WS_G     1792     // [8][8]
#define WS_g     1856     // [8]
#define WS_BW    1864     // [24]  b_w[k*3+m]
#define WS_Q00   1888
#define WS_WSUM  1889
#define WS_CB32  2048     // [64][32] : per n {w, pad3, cb[24], pad4}

__host__ __device__ constexpr int tidx(int i, int j) { return i*10 - i*(i+1)/2 + j; } // i<=j (upper packed, 10x10)
__host__ __device__ constexpr int lidx(int i, int j) { return i*(i+1)/2 + j; }        // i>=j (lower packed)

// ---------------- K1: precompute (1 block, 64 threads; GJ parallelized in LDS) ----------------
__global__ void k_pre(const float* __restrict__ bb, const float* __restrict__ w,
                      const float* __restrict__ lam, float* __restrict__ ws)
{
  __shared__ float s_w[64], s_sw[64], s_bw[24], s_barb[64][24];
  __shared__ float s_BtB[64];
  __shared__ float s_M[8][16];      // [A | Iv]
  __shared__ float s_u[8], s_g[8], s_red[64], s_wsum, s_s;
  const int t = threadIdx.x;
  const int i8 = t >> 3, j8 = t & 7;
  const float lv = lam[0];

  s_w[t]  = w[t];
  s_sw[t] = sqrtf(fmaxf(s_w[t], 0.0f));
  __syncthreads();
  if (t == 0) { float a = 0; for (int n = 0; n < 64; n++) a += s_w[n]; s_wsum = a; }
  __syncthreads();
  const float wsum = s_wsum;
  if (t < 24) {
    float a = 0;
    for (int n = 0; n < 64; n++) a += bb[t*64 + n] * s_w[n];
    s_bw[t] = a / wsum;
  }
  __syncthreads();
  for (int km = 0; km < 24; ++km)
    s_barb[t][km] = s_sw[t] * (bb[km*64 + t] - s_bw[km]);
  __syncthreads();
  {
    float a = 0;
    for (int n = 0; n < 64; n++)
      for (int j = 0; j < 3; j++)
        a += s_barb[n][i8*3 + j] * s_barb[n][j8*3 + j];
    s_BtB[t] = a;
  }
  __syncthreads();
  s_M[i8][j8]     = 2.0f * (s_BtB[t] + ((i8 == j8) ? lv : 0.0f));
  s_M[i8][8 + j8] = (i8 == j8) ? 1.0f : 0.0f;
#pragma unroll
  for (int k = 0; k < 8; k++) {
    __syncthreads();
    const float fk  = s_M[i8][k];
    const float piv = 1.0f / s_M[k][k];
    __syncthreads();
    if (i8 == k) { s_M[k][j8] *= piv; s_M[k][8 + j8] *= piv; }
    __syncthreads();
    if (i8 != k) {
      s_M[i8][j8]     -= fk * s_M[k][j8];
      s_M[i8][8 + j8] -= fk * s_M[k][8 + j8];
    }
  }
  __syncthreads();
  if (t < 8) {
    float a = 0;
#pragma unroll
    for (int j = 0; j < 8; j++) a += s_M[t][8 + j];
    s_u[t] = a;
  }
  __syncthreads();
  if (t == 0) {
    float s = 0;
#pragma unroll
    for (int j = 0; j < 8; j++) s += s_u[j];
    s_s = s;
  }
  __syncthreads();
  const float s = s_s;
  if (t < 8) s_g[t] = s_u[t] / s;
  const float Gel = s_M[i8][8 + j8] - s_u[i8] * s_u[j8] / s;
  ws[WS_G + t] = Gel;
  __syncthreads();
  s_red[t] = s_g[i8] * (s_BtB[t] + ((i8 == j8) ? lv : 0.0f)) * s_g[j8];
  __syncthreads();
  if (t == 0) {
    float a = 0;
    for (int n = 0; n < 64; n++) a += s_red[n];
    ws[WS_Q00]  = a;
    ws[WS_WSUM] = wsum;
  }
  if (t < 8)  ws[WS_g + t]  = s_g[t];
  if (t < 24) ws[WS_BW + t] = s_bw[t];
  {                                     // padded per-n coefficient row, t = n
    float* p = ws + WS_CB32 + t*32;
    p[0] = s_w[t]; p[1] = 0; p[2] = 0; p[3] = 0;
#pragma unroll
    for (int km = 0; km < 24; km++)
      p[4 + km] = s_sw[t] * s_barb[t][km];
#pragma unroll
    for (int i = 28; i < 32; i++) p[i] = 0;
  }
}

// ---------------- K2: fused build(n-split) + tridiag + quaternary Sturm + Cholesky inv-iter ----------------
// 256 threads = 64 batches x 4 subs. Sub owns n in [sub*16, sub*16+16) for the build;
// after F-butterfly every lane holds full F. FG/q_low keep the k-split (sub owns k2 in {2sub,2sub+1}).
__global__ __launch_bounds__(256, 2) void k_main(const float* __restrict__ y,
                                                 const float* __restrict__ ws,
                                                 float* __restrict__ out)
{
  __shared__ float s_cb[64*32];     // [n][32] {w,pad3,cb24,pad4}
  __shared__ float s_G[64], s_g8[8], s_bw[24];
  __shared__ float s_Q[55][66];
  const int t   = threadIdx.x;
  const int lb  = t >> 2;           // local batch 0..63
  const int sub = t & 3;
  const int b   = blockIdx.x * 64 + lb;

  for (int i = t; i < 64*32; i += 256) s_cb[i] = ws[WS_CB32 + i];
  if (t < 64) s_G[t]  = ws[WS_G + t];
  if (t < 8)  s_g8[t] = ws[WS_g + t];
  if (t >= 8 && t < 32) s_bw[t - 8] = ws[WS_BW + (t - 8)];
  const float q00v = ws[WS_Q00];
  const float wsum = ws[WS_WSUM];
  __syncthreads();

  // ---- build phase: n-split (each sub reads its n-quarter only) ----
  const float* yb = y + (size_t)b * 192;
  float F[24][3];
  float gw[6];
  float ywa[3] = {0, 0, 0};
#pragma unroll
  for (int i = 0; i < 24; i++) { F[i][0] = 0; F[i][1] = 0; F[i][2] = 0; }
#pragma unroll
  for (int i = 0; i < 6; i++) gw[i] = 0;

#pragma unroll
  for (int i4 = 0; i4 < 4; i4++) {
    const int n4 = sub*4 + i4;
    float4 v0 = reinterpret_cast<const float4*>(yb)[n4];
    float4 v1 = reinterpret_cast<const float4*>(yb + 64)[n4];
    float4 v2 = reinterpret_cast<const float4*>(yb + 128)[n4];
    float a0[4] = {v0.x, v0.y, v0.z, v0.w};
    float a1[4] = {v1.x, v1.y, v1.z, v1.w};
    float a2[4] = {v2.x, v2.y, v2.z, v2.w};
#pragma unroll
    for (int l = 0; l < 4; l++) {
      const int n = 4*n4 + l;
      const float4* row = reinterpret_cast<const float4*>(s_cb + n*32);
      float4 c0 = row[0];
      float4 ch[6];
#pragma unroll
      for (int cc = 0; cc < 6; cc++) {
        const int ci = 1 + ((cc + sub) & 3) + ((cc + sub) > 3 && (cc+sub) < 6 ? 4 : ((cc+sub) >= 6 ? ((cc+sub)-6) - ((cc+sub)&3) + 4 : 0)); // fallback below
        (void)ci;
      }
      // simple ordered reads (4-way bank alias ~1.5x acceptable)
#pragma unroll
      for (int cc = 0; cc < 6; cc++) ch[cc] = row[1 + cc];
      const float cb[24] = {ch[0].x, ch[0].y, ch[0].z, ch[0].w,
                            ch[1].x, ch[1].y, ch[1].z, ch[1].w,
                            ch[2].x, ch[2].y, ch[2].z, ch[2].w,
                            ch[3].x, ch[3].y, ch[3].z, ch[3].w,
                            ch[4].x, ch[4].y, ch[4].z, ch[4].w,
                            ch[5].x, ch[5].y, ch[5].z, ch[5].w};
      float ym0 = a0[l], ym1 = a1[l], ym2 = a2[l];
      float wn  = c0.x;
      float wy0 = wn*ym0, wy1 = wn*ym1, wy2 = wn*ym2;
      ywa[0] += wy0; ywa[1] += wy1; ywa[2] += wy2;
      gw[0] += wy0*ym0; gw[1] += wy0*ym1; gw[2] += wy0*ym2;
      gw[3] += wy1*ym1; gw[4] += wy1*ym2; gw[5] += wy2*ym2;
#pragma unroll
      for (int km = 0; km < 24; km++) {
        F[km][0] += cb[km]*ym0; F[km][1] += cb[km]*ym1; F[km][2] += cb[km]*ym2;
      }
    }
  }
  // butterfly partial sums across the 4 subs -> full F, gw, ywa in every lane
#pragma unroll
  for (int km = 0; km < 24; km++)
#pragma unroll
    for (int m = 0; m < 3; m++) {
      float v = F[km][m];
      v += __shfl_xor(v, 1);
      v += __shfl_xor(v, 2);
      F[km][m] = v;
    }
#pragma unroll
  for (int i = 0; i < 6; i++) { float v = gw[i]; v += __shfl_xor(v, 1); v += __shfl_xor(v, 2); gw[i] = v; }
#pragma unroll
  for (int i = 0; i < 3; i++) { float v = ywa[i]; v += __shfl_xor(v, 1); v += __shfl_xor(v, 2); ywa[i] = v; }

  const float iws = 1.0f / wsum;
  float yw[3] = {ywa[0]*iws, ywa[1]*iws, ywa[2]*iws};
  float Gram[6];
  Gram[0] = gw[0] - ywa[0]*ywa[0]*iws;
  Gram[1] = gw[1] - ywa[0]*ywa[1]*iws;
  Gram[2] = gw[2] - ywa[0]*ywa[2]*iws;
  Gram[3] = gw[3] - ywa[1]*ywa[1]*iws;
  Gram[4] = gw[4] - ywa[1]*ywa[2]*iws;
  Gram[5] = gw[5] - ywa[2]*ywa[2]*iws;

  if (sub == 0) s_Q[0][lb] = q00v;
  // q_top: full (redundant x4), distributed writes
#pragma unroll
  for (int e = 0; e < 9; e++) {
    const int j = e / 3, m = e % 3;
    float a = 0;
#pragma unroll
    for (int k = 0; k < 8; k++) a += s_g8[k] * F[k*3 + j][m];
    if ((e & 3) == sub) s_Q[tidx(0, 1 + e)][lb] = -a;
  }
  // own-k slice F6 (static cndmask selects; rows sub*6+kk)
  float F6[6][3];
#pragma unroll
  for (int kk = 0; kk < 6; kk++)
#pragma unroll
    for (int m = 0; m < 3; m++) {
      float x01 = (sub & 1) ? F[6 + kk][m]  : F[kk][m];
      float x23 = (sub & 1) ? F[18 + kk][m] : F[12 + kk][m];
      F6[kk][m] = (sub & 2) ? x23 : x01;
    }
  // FG rows for my k2 in {2sub, 2sub+1} from full F (registers)
  float FGr[2][9];
#pragma unroll
  for (int kk = 0; kk < 2; kk++) {
    float gcol[8];
#pragma unroll
    for (int k = 0; k < 8; k++) {
      float g01 = (sub & 1) ? s_G[k*8 + 2 + kk] : s_G[k*8 + 0 + kk];
      float g23 = (sub & 1) ? s_G[k*8 + 6 + kk] : s_G[k*8 + 4 + kk];
      gcol[k] = (sub & 2) ? g23 : g01;
    }
#pragma unroll
    for (int e = 0; e < 9; e++) {
      const int j = e / 3, m = e % 3;
      float a = 0;
#pragma unroll
      for (int k = 0; k < 8; k++) a += gcol[k] * F[k*3 + j][m];
      FGr[kk][e] = a;
    }
  }
  // q_low: partial over own k2 pair, butterfly, distributed writes
#pragma unroll
  for (int e = 0; e < 9; e++)
#pragma unroll
    for (int f = e; f < 9; f++) {
      const int j = e/3, m = e%3, j2 = f/3, m2 = f%3;
      float p = FGr[0][e] * F6[j2][m2] + FGr[1][e] * F6[3 + j2][m2];
      p += __shfl_xor(p, 1);
      p += __shfl_xor(p, 2);
      if ((tidx(1 + e, 1 + f) & 3) == sub) {
        const float gterm = (j == j2) ? Gram[(m <= m2) ? (m*3 - m*(m+1)/2 + m2) : (m2*3 - m2*(m2+1)/2 + m)] : 0.0f;
        s_Q[tidx(1 + e, 1 + f)][lb] = -2.0f*p + gterm;
      }
    }
  __syncthreads();

  // ---- tridiagonalize Q (register copy) via Householder: T = (ad[10], b2[9]) ----
  float Mm[55];
#pragma unroll
  for (int i = 0; i < 10; i++)
#pragma unroll
    for (int j = 0; j <= i; j++)
      Mm[lidx(i,j)] = s_Q[tidx(j,i)][lb];

  float ad[10], b2[9];
#pragma unroll
  for (int j = 0; j < 8; j++) {
    float s2 = 0;
#pragma unroll
    for (int i = j + 1; i < 10; i++) s2 += Mm[lidx(i,j)] * Mm[lidx(i,j)];
    const float x0 = Mm[lidx(j+1,j)];
    const float anorm = __builtin_amdgcn_sqrtf(s2);
    const float alpha = (x0 > 0.0f) ? -anorm : anorm;
    const float uu = s2 - alpha * x0;
    const float beta = (uu > 1e-35f) ? __builtin_amdgcn_rcpf(uu) : 0.0f;
    float u[10], p[10];
    u[j+1] = x0 - alpha;
#pragma unroll
    for (int i = j + 2; i < 10; i++) u[i] = Mm[lidx(i,j)];
#pragma unroll
    for (int i = j + 1; i < 10; i++) {
      float acc = 0;
#pragma unroll
      for (int k = j + 1; k < 10; k++) acc += Mm[(i >= k) ? lidx(i,k) : lidx(k,i)] * u[k];
      p[i] = beta * acc;
    }
    float K = 0;
#pragma unroll
    for (int i = j + 1; i < 10; i++) K += u[i] * p[i];
    K *= 0.5f * beta;
#pragma unroll
    for (int i = j + 1; i < 10; i++) p[i] -= K * u[i];
#pragma unroll
    for (int i = j + 1; i < 10; i++)
#pragma unroll
      for (int k = j + 1; k <= i; k++)
        Mm[lidx(i,k)] -= u[i]*p[k] + p[i]*u[k];
    ad[j] = Mm[lidx(j,j)];
    b2[j] = s2;
  }
  ad[8] = Mm[lidx(8,8)];
  ad[9] = Mm[lidx(9,9)];
  b2[8] = Mm[lidx(9,8)] * Mm[lidx(9,8)];

  float b2max = b2[0];
#pragma unroll
  for (int i = 1; i < 9; i++) b2max = fmaxf(b2max, b2[i]);
  const float pm = 1e-20f * b2max + 1e-30f;

  // ---- phase A: quaternary Sturm bisection on T (11 rounds == 22 bits) ----
  float lo = 0.0f, hi = s_Q[0][lb];
#pragma unroll
  for (int j = 1; j < 10; j++) hi = fminf(hi, s_Q[tidx(j,j)][lb]);

  const int base = (t & 63) & ~3;
  const float subf = (sub == 0) ? 2.0f : (float)sub;
  for (int round = 0; round < 11; ++round) {
    const float quart = 0.25f * (hi - lo);
    const float mid = lo + quart * subf;
    int neg = 0;
    float d = ad[0] - mid;
    neg += (d < 0.0f) ? 1 : 0;
#pragma unroll
    for (int i = 1; i < 10; i++) {
      d = (fabsf(d) < pm) ? -pm : d;
      d = ad[i] - mid - b2[i-1] * __builtin_amdgcn_rcpf(d);
      neg += (d < 0.0f) ? 1 : 0;
    }
    const int n1 = __shfl(neg, base | 1);
    const int n2 = __shfl(neg, base | 2);
    const int n3 = __shfl(neg, base | 3);
    const float m1 = lo + quart, m2v = lo + 2.0f*quart, m3 = lo + 3.0f*quart;
    const float nlo = (n3 == 0) ? m3 : (n2 == 0) ? m2v : (n1 == 0) ? m1 : lo;
    const float nhi = (n1 > 0) ? m1 : (n2 > 0) ? m2v : (n3 > 0) ? m3 : hi;
    lo = nlo; hi = nhi;
  }

  // ---- phase B: Cholesky of (Q - sigma I) + 3 inverse iterations (redundant x4) ----
  float M[55], id[10];
#pragma unroll
  for (int i = 0; i < 10; i++)
#pragma unroll
    for (int j = 0; j <= i; j++)
      M[lidx(i,j)] = s_Q[tidx(j,i)][lb];
  float tr = 0.0f;
#pragma unroll
  for (int i = 0; i < 10; i++) tr += M[lidx(i,i)];
  const float delta = 1e-5f * fabsf(tr) + 1e-30f;
  const float sigma = lo - delta;
#pragma unroll
  for (int i = 0; i < 10; i++) M[lidx(i,i)] -= sigma;

#pragma unroll
  for (int j = 0; j < 10; j++) {
    float d = M[lidx(j,j)];
#pragma unroll
    for (int t2 = 0; t2 < j; t2++) d -= M[lidx(j,t2)] * M[lidx(j,t2)];
    d = fmaxf(d, 1e-30f);
    float is = __builtin_amdgcn_rsqf(d);
    id[j] = is;
#pragma unroll
    for (int i = j + 1; i < 10; i++) {
      float a = M[lidx(i,j)];
#pragma unroll
      for (int t2 = 0; t2 < j; t2++) a -= M[lidx(i,t2)] * M[lidx(j,t2)];
      M[lidx(i,j)] = a * is;
    }
  }

  float x[10];
#pragma unroll
  for (int i = 0; i < 10; i++) x[i] = 1.0f;
#pragma unroll
  for (int it = 0; it < 3; ++it) {
#pragma unroll
    for (int i = 0; i < 10; i++) {
      float a = x[i];
#pragma unroll
      for (int j = 0; j < i; j++) a -= M[lidx(i,j)] * x[j];
      x[i] = a * id[i];
    }
#pragma unroll
    for (int i = 9; i >= 0; i--) {
      float a = x[i];
#pragma unroll
      for (int j = i + 1; j < 10; j++) a -= M[lidx(j,i)] * x[j];
      x[i] = a * id[i];
    }
    float s2 = 0;
#pragma unroll
    for (int i = 0; i < 10; i++) s2 += x[i]*x[i];
    float sc = __builtin_amdgcn_rsqf(s2 + 1e-38f);
#pragma unroll
    for (int i = 0; i < 10; i++) x[i] *= sc;
  }

  // ---- epilogue: R, c, t ----
  const float inv0 = __builtin_amdgcn_rcpf(x[0]);
  float R[3][3];
#pragma unroll
  for (int r = 0; r < 3; r++)
#pragma unroll
    for (int cc = 0; cc < 3; cc++)
      R[r][cc] = x[1 + 3*cc + r] * inv0;

  float cv[2];
#pragma unroll
  for (int kk = 0; kk < 2; kk++) {
    const int k = sub*2 + kk;
    float a = 0;
#pragma unroll
    for (int e = 0; e < 9; e++) a += x[1 + e] * FGr[kk][e];
    cv[kk] = 2.0f * inv0 * a + s_g8[k];
    out[(size_t)12*Bn + (size_t)b*8 + k] = cv[kk];
  }
  float um0 = s_bw[(sub*2)*3 + 0]*cv[0] + s_bw[(sub*2 + 1)*3 + 0]*cv[1];
  float um1 = s_bw[(sub*2)*3 + 1]*cv[0] + s_bw[(sub*2 + 1)*3 + 1]*cv[1];
  float um2 = s_bw[(sub*2)*3 + 2]*cv[0] + s_bw[(sub*2 + 1)*3 + 2]*cv[1];
  um0 += __shfl_xor(um0, 1); um0 += __shfl_xor(um0, 2);
  um1 += __shfl_xor(um1, 1); um1 += __shfl_xor(um1, 2);
  um2 += __shfl_xor(um2, 1); um2 += __shfl_xor(um2, 2);

#pragma unroll
  for (int r = 0; r < 3; r++)
#pragma unroll
    for (int cc = 0; cc < 3; cc++)
      if (((r*3 + cc) & 3) == sub)
        out[(size_t)b*9 + r*3 + cc] = R[r][cc];
  if (sub == 0) {
#pragma unroll
    for (int r = 0; r < 3; r++)
      out[(size_t)9*Bn + (size_t)b*3 + r] = yw[r] - (R[r][0]*um0 + R[r][1]*um1 + R[r][2]*um2);
  }
}

extern "C" void kernel_launch(void* const* d_in, const int* in_sizes, int n_in,
                              void* d_out, int out_size, void* d_ws, size_t ws_size,
                              hipStream_t stream) {
  const float* y   = (const float*)d_in[0];
  const float* bb  = (const float*)d_in[1];
  const float* w   = (const float*)d_in[2];
  const float* lam = (const float*)d_in[3];
  float* ws  = (float*)d_ws;
  float* out = (float*)d_out;
  k_pre <<<1,      64, 0, stream>>>(bb, w, lam, ws);
  k_main<<<Bn/64, 256, 0, stream>>>(y, ws, out);
}

// Round 19
// 42.586 us; speedup vs baseline: 1.5476x; 1.0051x over previous
//
#include <hip/hip_runtime.h>
#include <math.h>

static constexpr int Bn = 32768;

// ws layout (floats)
#define WS_G     1792     // [8][8]
#define WS_g     1856     // [8]
#define WS_BW    1864     // [24]  b_w[k*3+m]
#define WS_Q00   1888
#define WS_WSUM  1889
#define WS_CB4   2048     // [4][520] : sub-plane s holds its n-quarter {per ni: w, pad3, cb[24], pad4}

__host__ __device__ constexpr int tidx(int i, int j) { return i*10 - i*(i+1)/2 + j; } // i<=j (upper packed, 10x10)
__host__ __device__ constexpr int lidx(int i, int j) { return i*(i+1)/2 + j; }        // i>=j (lower packed)

// ---------------- K1: precompute (1 block, 64 threads; GJ parallelized in LDS) ----------------
__global__ void k_pre(const float* __restrict__ bb, const float* __restrict__ w,
                      const float* __restrict__ lam, float* __restrict__ ws)
{
  __shared__ float s_w[64], s_sw[64], s_bw[24], s_barb[64][24];
  __shared__ float s_BtB[64];
  __shared__ float s_M[8][16];      // [A | Iv]
  __shared__ float s_u[8], s_g[8], s_red[64], s_wsum, s_s;
  const int t = threadIdx.x;
  const int i8 = t >> 3, j8 = t & 7;
  const float lv = lam[0];

  s_w[t]  = w[t];
  s_sw[t] = sqrtf(fmaxf(s_w[t], 0.0f));
  __syncthreads();
  if (t == 0) { float a = 0; for (int n = 0; n < 64; n++) a += s_w[n]; s_wsum = a; }
  __syncthreads();
  const float wsum = s_wsum;
  if (t < 24) {
    float a = 0;
    for (int n = 0; n < 64; n++) a += bb[t*64 + n] * s_w[n];
    s_bw[t] = a / wsum;
  }
  __syncthreads();
  for (int km = 0; km < 24; ++km)
    s_barb[t][km] = s_sw[t] * (bb[km*64 + t] - s_bw[km]);
  __syncthreads();
  {
    float a = 0;
    for (int n = 0; n < 64; n++)
      for (int j = 0; j < 3; j++)
        a += s_barb[n][i8*3 + j] * s_barb[n][j8*3 + j];
    s_BtB[t] = a;
  }
  __syncthreads();
  s_M[i8][j8]     = 2.0f * (s_BtB[t] + ((i8 == j8) ? lv : 0.0f));
  s_M[i8][8 + j8] = (i8 == j8) ? 1.0f : 0.0f;
#pragma unroll
  for (int k = 0; k < 8; k++) {
    __syncthreads();
    const float fk  = s_M[i8][k];
    const float piv = 1.0f / s_M[k][k];
    __syncthreads();
    if (i8 == k) { s_M[k][j8] *= piv; s_M[k][8 + j8] *= piv; }
    __syncthreads();
    if (i8 != k) {
      s_M[i8][j8]     -= fk * s_M[k][j8];
      s_M[i8][8 + j8] -= fk * s_M[k][8 + j8];
    }
  }
  __syncthreads();
  if (t < 8) {
    float a = 0;
#pragma unroll
    for (int j = 0; j < 8; j++) a += s_M[t][8 + j];
    s_u[t] = a;
  }
  __syncthreads();
  if (t == 0) {
    float s = 0;
#pragma unroll
    for (int j = 0; j < 8; j++) s += s_u[j];
    s_s = s;
  }
  __syncthreads();
  const float s = s_s;
  if (t < 8) s_g[t] = s_u[t] / s;
  const float Gel = s_M[i8][8 + j8] - s_u[i8] * s_u[j8] / s;
  ws[WS_G + t] = Gel;
  __syncthreads();
  s_red[t] = s_g[i8] * (s_BtB[t] + ((i8 == j8) ? lv : 0.0f)) * s_g[j8];
  __syncthreads();
  if (t == 0) {
    float a = 0;
    for (int n = 0; n < 64; n++) a += s_red[n];
    ws[WS_Q00]  = a;
    ws[WS_WSUM] = wsum;
  }
  if (t < 8)  ws[WS_g + t]  = s_g[t];
  if (t < 24) ws[WS_BW + t] = s_bw[t];
  {                                     // per-sub plane coefficient row, t = n
    float* p = ws + WS_CB4 + (t >> 4)*520 + (t & 15)*32;
    p[0] = s_w[t]; p[1] = 0; p[2] = 0; p[3] = 0;
#pragma unroll
    for (int km = 0; km < 24; km++)
      p[4 + km] = s_sw[t] * s_barb[t][km];
#pragma unroll
    for (int i = 28; i < 32; i++) p[i] = 0;
  }
}

// ---------------- K2: fused build(n-split) + tridiag + quaternary Sturm + Cholesky inv-iter ----------------
// 256 threads = 64 batches x 4 subs. Sub owns n in [sub*16, sub*16+16) for the build;
// after F-butterfly every lane holds full F. FG/q_low keep the k-split (sub owns k2 in {2sub,2sub+1}).
__global__ __launch_bounds__(256, 2) void k_main(const float* __restrict__ y,
                                                 const float* __restrict__ ws,
                                                 float* __restrict__ out)
{
  __shared__ float s_cb[4*520];     // per-sub planes, stride 520 (8-bank offset between subs)
  __shared__ float s_G[64], s_g8[8], s_bw[24];
  __shared__ float s_Q[55][66];
  const int t   = threadIdx.x;
  const int lb  = t >> 2;           // local batch 0..63
  const int sub = t & 3;
  const int b   = blockIdx.x * 64 + lb;

  for (int i = t; i < 4*520; i += 256) s_cb[i] = ws[WS_CB4 + i];
  if (t < 64) s_G[t]  = ws[WS_G + t];
  if (t < 8)  s_g8[t] = ws[WS_g + t];
  if (t >= 8 && t < 32) s_bw[t - 8] = ws[WS_BW + (t - 8)];
  const float q00v = ws[WS_Q00];
  const float wsum = ws[WS_WSUM];
  __syncthreads();

  // ---- build phase: n-split (each sub reads its n-quarter only) ----
  const float* yb = y + (size_t)b * 192;
  float F[24][3];
  float gw[6];
  float ywa[3] = {0, 0, 0};
#pragma unroll
  for (int i = 0; i < 24; i++) { F[i][0] = 0; F[i][1] = 0; F[i][2] = 0; }
#pragma unroll
  for (int i = 0; i < 6; i++) gw[i] = 0;

  const float* plane = s_cb + sub*520;
#pragma unroll
  for (int i4 = 0; i4 < 4; i4++) {
    const int n4 = sub*4 + i4;
    float4 v0 = reinterpret_cast<const float4*>(yb)[n4];
    float4 v1 = reinterpret_cast<const float4*>(yb + 64)[n4];
    float4 v2 = reinterpret_cast<const float4*>(yb + 128)[n4];
    float a0[4] = {v0.x, v0.y, v0.z, v0.w};
    float a1[4] = {v1.x, v1.y, v1.z, v1.w};
    float a2[4] = {v2.x, v2.y, v2.z, v2.w};
#pragma unroll
    for (int l = 0; l < 4; l++) {
      const int ni = 4*i4 + l;                 // local n within my quarter
      const float4* row = reinterpret_cast<const float4*>(plane + ni*32);
      float4 c0 = row[0];
      float4 ch[6];
#pragma unroll
      for (int cc = 0; cc < 6; cc++) ch[cc] = row[1 + cc];
      const float cb[24] = {ch[0].x, ch[0].y, ch[0].z, ch[0].w,
                            ch[1].x, ch[1].y, ch[1].z, ch[1].w,
                            ch[2].x, ch[2].y, ch[2].z, ch[2].w,
                            ch[3].x, ch[3].y, ch[3].z, ch[3].w,
                            ch[4].x, ch[4].y, ch[4].z, ch[4].w,
                            ch[5].x, ch[5].y, ch[5].z, ch[5].w};
      float ym0 = a0[l], ym1 = a1[l], ym2 = a2[l];
      float wn  = c0.x;
      float wy0 = wn*ym0, wy1 = wn*ym1, wy2 = wn*ym2;
      ywa[0] += wy0; ywa[1] += wy1; ywa[2] += wy2;
      gw[0] += wy0*ym0; gw[1] += wy0*ym1; gw[2] += wy0*ym2;
      gw[3] += wy1*ym1; gw[4] += wy1*ym2; gw[5] += wy2*ym2;
#pragma unroll
      for (int km = 0; km < 24; km++) {
        F[km][0] += cb[km]*ym0; F[km][1] += cb[km]*ym1; F[km][2] += cb[km]*ym2;
      }
    }
  }
  // butterfly partial sums across the 4 subs -> full F, gw, ywa in every lane
#pragma unroll
  for (int km = 0; km < 24; km++)
#pragma unroll
    for (int m = 0; m < 3; m++) {
      float v = F[km][m];
      v += __shfl_xor(v, 1);
      v += __shfl_xor(v, 2);
      F[km][m] = v;
    }
#pragma unroll
  for (int i = 0; i < 6; i++) { float v = gw[i]; v += __shfl_xor(v, 1); v += __shfl_xor(v, 2); gw[i] = v; }
#pragma unroll
  for (int i = 0; i < 3; i++) { float v = ywa[i]; v += __shfl_xor(v, 1); v += __shfl_xor(v, 2); ywa[i] = v; }

  const float iws = 1.0f / wsum;
  float yw[3] = {ywa[0]*iws, ywa[1]*iws, ywa[2]*iws};
  float Gram[6];
  Gram[0] = gw[0] - ywa[0]*ywa[0]*iws;
  Gram[1] = gw[1] - ywa[0]*ywa[1]*iws;
  Gram[2] = gw[2] - ywa[0]*ywa[2]*iws;
  Gram[3] = gw[3] - ywa[1]*ywa[1]*iws;
  Gram[4] = gw[4] - ywa[1]*ywa[2]*iws;
  Gram[5] = gw[5] - ywa[2]*ywa[2]*iws;

  if (sub == 0) s_Q[0][lb] = q00v;
  // q_top: full (redundant x4), distributed writes
#pragma unroll
  for (int e = 0; e < 9; e++) {
    const int j = e / 3, m = e % 3;
    float a = 0;
#pragma unroll
    for (int k = 0; k < 8; k++) a += s_g8[k] * F[k*3 + j][m];
    if ((e & 3) == sub) s_Q[tidx(0, 1 + e)][lb] = -a;
  }
  // own-k slice F6 (static cndmask selects; rows sub*6+kk)
  float F6[6][3];
#pragma unroll
  for (int kk = 0; kk < 6; kk++)
#pragma unroll
    for (int m = 0; m < 3; m++) {
      float x01 = (sub & 1) ? F[6 + kk][m]  : F[kk][m];
      float x23 = (sub & 1) ? F[18 + kk][m] : F[12 + kk][m];
      F6[kk][m] = (sub & 2) ? x23 : x01;
    }
  // FG rows for my k2 in {2sub, 2sub+1} from full F (registers)
  float FGr[2][9];
#pragma unroll
  for (int kk = 0; kk < 2; kk++) {
    float gcol[8];
#pragma unroll
    for (int k = 0; k < 8; k++) {
      float g01 = (sub & 1) ? s_G[k*8 + 2 + kk] : s_G[k*8 + 0 + kk];
      float g23 = (sub & 1) ? s_G[k*8 + 6 + kk] : s_G[k*8 + 4 + kk];
      gcol[k] = (sub & 2) ? g23 : g01;
    }
#pragma unroll
    for (int e = 0; e < 9; e++) {
      const int j = e / 3, m = e % 3;
      float a = 0;
#pragma unroll
      for (int k = 0; k < 8; k++) a += gcol[k] * F[k*3 + j][m];
      FGr[kk][e] = a;
    }
  }
  // q_low: partial over own k2 pair, butterfly, distributed writes
#pragma unroll
  for (int e = 0; e < 9; e++)
#pragma unroll
    for (int f = e; f < 9; f++) {
      const int j = e/3, m = e%3, j2 = f/3, m2 = f%3;
      float p = FGr[0][e] * F6[j2][m2] + FGr[1][e] * F6[3 + j2][m2];
      p += __shfl_xor(p, 1);
      p += __shfl_xor(p, 2);
      if ((tidx(1 + e, 1 + f) & 3) == sub) {
        const float gterm = (j == j2) ? Gram[(m <= m2) ? (m*3 - m*(m+1)/2 + m2) : (m2*3 - m2*(m2+1)/2 + m)] : 0.0f;
        s_Q[tidx(1 + e, 1 + f)][lb] = -2.0f*p + gterm;
      }
    }
  __syncthreads();

  // ---- tridiagonalize Q (register copy) via Householder: T = (ad[10], b2[9]) ----
  float Mm[55];
#pragma unroll
  for (int i = 0; i < 10; i++)
#pragma unroll
    for (int j = 0; j <= i; j++)
      Mm[lidx(i,j)] = s_Q[tidx(j,i)][lb];

  float ad[10], b2[9];
#pragma unroll
  for (int j = 0; j < 8; j++) {
    float s2 = 0;
#pragma unroll
    for (int i = j + 1; i < 10; i++) s2 += Mm[lidx(i,j)] * Mm[lidx(i,j)];
    const float x0 = Mm[lidx(j+1,j)];
    const float anorm = __builtin_amdgcn_sqrtf(s2);
    const float alpha = (x0 > 0.0f) ? -anorm : anorm;
    const float uu = s2 - alpha * x0;
    const float beta = (uu > 1e-35f) ? __builtin_amdgcn_rcpf(uu) : 0.0f;
    float u[10], p[10];
    u[j+1] = x0 - alpha;
#pragma unroll
    for (int i = j + 2; i < 10; i++) u[i] = Mm[lidx(i,j)];
#pragma unroll
    for (int i = j + 1; i < 10; i++) {
      float acc = 0;
#pragma unroll
      for (int k = j + 1; k < 10; k++) acc += Mm[(i >= k) ? lidx(i,k) : lidx(k,i)] * u[k];
      p[i] = beta * acc;
    }
    float K = 0;
#pragma unroll
    for (int i = j + 1; i < 10; i++) K += u[i] * p[i];
    K *= 0.5f * beta;
#pragma unroll
    for (int i = j + 1; i < 10; i++) p[i] -= K * u[i];
#pragma unroll
    for (int i = j + 1; i < 10; i++)
#pragma unroll
      for (int k = j + 1; k <= i; k++)
        Mm[lidx(i,k)] -= u[i]*p[k] + p[i]*u[k];
    ad[j] = Mm[lidx(j,j)];
    b2[j] = s2;
  }
  ad[8] = Mm[lidx(8,8)];
  ad[9] = Mm[lidx(9,9)];
  b2[8] = Mm[lidx(9,8)] * Mm[lidx(9,8)];

  float b2max = b2[0];
#pragma unroll
  for (int i = 1; i < 9; i++) b2max = fmaxf(b2max, b2[i]);
  const float pm = 1e-20f * b2max + 1e-30f;

  // ---- phase A: quaternary Sturm bisection on T (11 rounds == 22 bits) ----
  float lo = 0.0f, hi = s_Q[0][lb];
#pragma unroll
  for (int j = 1; j < 10; j++) hi = fminf(hi, s_Q[tidx(j,j)][lb]);

  const int base = (t & 63) & ~3;
  const float subf = (sub == 0) ? 2.0f : (float)sub;
  for (int round = 0; round < 11; ++round) {
    const float quart = 0.25f * (hi - lo);
    const float mid = lo + quart * subf;
    int neg = 0;
    float d = ad[0] - mid;
    neg += (d < 0.0f) ? 1 : 0;
#pragma unroll
    for (int i = 1; i < 10; i++) {
      d = (fabsf(d) < pm) ? -pm : d;
      d = ad[i] - mid - b2[i-1] * __builtin_amdgcn_rcpf(d);
      neg += (d < 0.0f) ? 1 : 0;
    }
    const int n1 = __shfl(neg, base | 1);
    const int n2 = __shfl(neg, base | 2);
    const int n3 = __shfl(neg, base | 3);
    const float m1 = lo + quart, m2v = lo + 2.0f*quart, m3 = lo + 3.0f*quart;
    const float nlo = (n3 == 0) ? m3 : (n2 == 0) ? m2v : (n1 == 0) ? m1 : lo;
    const float nhi = (n1 > 0) ? m1 : (n2 > 0) ? m2v : (n3 > 0) ? m3 : hi;
    lo = nlo; hi = nhi;
  }

  // ---- phase B: Cholesky of (Q - sigma I) + 3 inverse iterations (redundant x4) ----
  float M[55], id[10];
#pragma unroll
  for (int i = 0; i < 10; i++)
#pragma unroll
    for (int j = 0; j <= i; j++)
      M[lidx(i,j)] = s_Q[tidx(j,i)][lb];
  float tr = 0.0f;
#pragma unroll
  for (int i = 0; i < 10; i++) tr += M[lidx(i,i)];
  const float delta = 1e-5f * fabsf(tr) + 1e-30f;
  const float sigma = lo - delta;
#pragma unroll
  for (int i = 0; i < 10; i++) M[lidx(i,i)] -= sigma;

#pragma unroll
  for (int j = 0; j < 10; j++) {
    float d = M[lidx(j,j)];
#pragma unroll
    for (int t2 = 0; t2 < j; t2++) d -= M[lidx(j,t2)] * M[lidx(j,t2)];
    d = fmaxf(d, 1e-30f);
    float is = __builtin_amdgcn_rsqf(d);
    id[j] = is;
#pragma unroll
    for (int i = j + 1; i < 10; i++) {
      float a = M[lidx(i,j)];
#pragma unroll
      for (int t2 = 0; t2 < j; t2++) a -= M[lidx(i,t2)] * M[lidx(j,t2)];
      M[lidx(i,j)] = a * is;
    }
  }

  float x[10];
#pragma unroll
  for (int i = 0; i < 10; i++) x[i] = 1.0f;
#pragma unroll
  for (int it = 0; it < 3; ++it) {
#pragma unroll
    for (int i = 0; i < 10; i++) {
      float a = x[i];
#pragma unroll
      for (int j = 0; j < i; j++) a -= M[lidx(i,j)] * x[j];
      x[i] = a * id[i];
    }
#pragma unroll
    for (int i = 9; i >= 0; i--) {
      float a = x[i];
#pragma unroll
      for (int j = i + 1; j < 10; j++) a -= M[lidx(j,i)] * x[j];
      x[i] = a * id[i];
    }
    float s2 = 0;
#pragma unroll
    for (int i = 0; i < 10; i++) s2 += x[i]*x[i];
    float sc = __builtin_amdgcn_rsqf(s2 + 1e-38f);
#pragma unroll
    for (int i = 0; i < 10; i++) x[i] *= sc;
  }

  // ---- epilogue: R, c, t ----
  const float inv0 = __builtin_amdgcn_rcpf(x[0]);
  float R[3][3];
#pragma unroll
  for (int r = 0; r < 3; r++)
#pragma unroll
    for (int cc = 0; cc < 3; cc++)
      R[r][cc] = x[1 + 3*cc + r] * inv0;

  float cv[2];
#pragma unroll
  for (int kk = 0; kk < 2; kk++) {
    const int k = sub*2 + kk;
    float a = 0;
#pragma unroll
    for (int e = 0; e < 9; e++) a += x[1 + e] * FGr[kk][e];
    cv[kk] = 2.0f * inv0 * a + s_g8[k];
    out[(size_t)12*Bn + (size_t)b*8 + k] = cv[kk];
  }
  float um0 = s_bw[(sub*2)*3 + 0]*cv[0] + s_bw[(sub*2 + 1)*3 + 0]*cv[1];
  float um1 = s_bw[(sub*2)*3 + 1]*cv[0] + s_bw[(sub*2 + 1)*3 + 1]*cv[1];
  float um2 = s_bw[(sub*2)*3 + 2]*cv[0] + s_bw[(sub*2 + 1)*3 + 2]*cv[1];
  um0 += __shfl_xor(um0, 1); um0 += __shfl_xor(um0, 2);
  um1 += __shfl_xor(um1, 1); um1 += __shfl_xor(um1, 2);
  um2 += __shfl_xor(um2, 1); um2 += __shfl_xor(um2, 2);

#pragma unroll
  for (int r = 0; r < 3; r++)
#pragma unroll
    for (int cc = 0; cc < 3; cc++)
      if (((r*3 + cc) & 3) == sub)
        out[(size_t)b*9 + r*3 + cc] = R[r][cc];
  if (sub == 0) {
#pragma unroll
    for (int r = 0; r < 3; r++)
      out[(size_t)9*Bn + (size_t)b*3 + r] = yw[r] - (R[r][0]*um0 + R[r][1]*um1 + R[r][2]*um2);
  }
}

extern "C" void kernel_launch(void* const* d_in, const int* in_sizes, int n_in,
                              void* d_out, int out_size, void* d_ws, size_t ws_size,
                              hipStream_t stream) {
  const float* y   = (const float*)d_in[0];
  const float* bb  = (const float*)d_in[1];
  const float* w   = (const float*)d_in[2];
  const float* lam = (const float*)d_in[3];
  float* ws  = (float*)d_ws;
  float* out = (float*)d_out;
  k_pre <<<1,      64, 0, stream>>>(bb, w, lam, ws);
  k_main<<<Bn/64, 256, 0, stream>>>(y, ws, out);
}

// Round 20
// 38.502 us; speedup vs baseline: 1.7118x; 1.1061x over previous
//
#include <hip/hip_runtime.h>
#include <math.h>

static constexpr int Bn = 32768;

__host__ __device__ constexpr int tidx(int i, int j) { return i*10 - i*(i+1)/2 + j; } // i<=j (upper packed, 10x10)
__host__ __device__ constexpr int lidx(int i, int j) { return i*(i+1)/2 + j; }        // i>=j (lower packed)

// ---------------- fused: per-block precompute + build(n-split) + tridiag + quaternary Sturm + Cholesky ----------------
// 256 threads = 64 batches x 4 subs. Precompute runs redundantly per block (t<64 active) into LDS.
__global__ __launch_bounds__(256, 2) void k_main(const float* __restrict__ y,
                                                 const float* __restrict__ bb,
                                                 const float* __restrict__ w,
                                                 const float* __restrict__ lam,
                                                 float* __restrict__ out)
{
  // precompute scratch
  __shared__ float s_w[64], s_sw[64], s_barb[64][24];
  __shared__ float s_BtB[64];
  __shared__ float s_M[8][16];      // [A | Iv]
  __shared__ float s_u[8], s_red[64];
  __shared__ float s_wsum, s_q00;
  // main tables
  __shared__ float s_cb[4*520];     // per-sub planes, stride 520
  __shared__ float s_G[64], s_g8[8], s_bw[24];
  __shared__ float s_Q[55][66];

  const int t   = threadIdx.x;
  const bool act = (t < 64);
  const int i8 = (t & 63) >> 3, j8 = t & 7;
  const float lv = lam[0];

  // ---- inlined k_pre (barriers at block level; work predicated on act) ----
  if (act) {
    s_w[t]  = w[t];
    s_sw[t] = sqrtf(fmaxf(w[t], 0.0f));
  }
  __syncthreads();
  if (t == 0) { float a = 0; for (int n = 0; n < 64; n++) a += s_w[n]; s_wsum = a; }
  __syncthreads();
  const float wsum = s_wsum;
  if (t < 24) {                       // b_w[k*3+m]
    float a = 0;
    for (int n = 0; n < 64; n++) a += bb[t*64 + n] * s_w[n];
    s_bw[t] = a / wsum;
  }
  __syncthreads();
  if (act)
    for (int km = 0; km < 24; ++km)
      s_barb[t][km] = s_sw[t] * (bb[km*64 + t] - s_bw[km]);
  __syncthreads();
  if (act) {
    float a = 0;
    for (int n = 0; n < 64; n++)
      for (int j = 0; j < 3; j++)
        a += s_barb[n][i8*3 + j] * s_barb[n][j8*3 + j];
    s_BtB[t] = a;
  }
  __syncthreads();
  if (act) {
    s_M[i8][j8]     = 2.0f * (s_BtB[t] + ((i8 == j8) ? lv : 0.0f));
    s_M[i8][8 + j8] = (i8 == j8) ? 1.0f : 0.0f;
  }
#pragma unroll
  for (int k = 0; k < 8; k++) {
    __syncthreads();
    float fk = 0.0f, piv = 1.0f;
    if (act) { fk = s_M[i8][k]; piv = 1.0f / s_M[k][k]; }
    __syncthreads();
    if (act && i8 == k) { s_M[k][j8] *= piv; s_M[k][8 + j8] *= piv; }
    __syncthreads();
    if (act && i8 != k) {
      s_M[i8][j8]     -= fk * s_M[k][j8];
      s_M[i8][8 + j8] -= fk * s_M[k][8 + j8];
    }
  }
  __syncthreads();
  if (t < 8) {
    float a = 0;
#pragma unroll
    for (int j = 0; j < 8; j++) a += s_M[t][8 + j];
    s_u[t] = a;
  }
  __syncthreads();
  if (t == 0) {
    float s = 0;
#pragma unroll
    for (int j = 0; j < 8; j++) s += s_u[j];
    s_red[0] = s;                   // reuse s_red[0] as the scalar s
  }
  __syncthreads();
  {
    const float s = s_red[0];
    if (t < 8) s_g8[t] = s_u[t] / s;
    if (act) s_G[t] = s_M[i8][8 + j8] - s_u[i8] * s_u[j8] / s;
  }
  __syncthreads();
  if (act) s_red[t] = s_g8[i8] * (s_BtB[t] + ((i8 == j8) ? lv : 0.0f)) * s_g8[j8];
  __syncthreads();
  if (t == 0) {
    float a = 0;
    for (int n = 0; n < 64; n++) a += s_red[n];
    s_q00 = a;
  }
  if (act) {                          // per-sub plane coefficient row, t = n
    float* p = s_cb + (t >> 4)*520 + (t & 15)*32;
    p[0] = s_w[t]; p[1] = 0; p[2] = 0; p[3] = 0;
#pragma unroll
    for (int km = 0; km < 24; km++)
      p[4 + km] = s_sw[t] * s_barb[t][km];
#pragma unroll
    for (int i = 28; i < 32; i++) p[i] = 0;
  }
  __syncthreads();
  const float q00v = s_q00;

  // ---- build phase: n-split (each sub reads its n-quarter only) ----
  const int lb  = t >> 2;           // local batch 0..63
  const int sub = t & 3;
  const int b   = blockIdx.x * 64 + lb;
  const float* yb = y + (size_t)b * 192;
  float F[24][3];
  float gw[6];
  float ywa[3] = {0, 0, 0};
#pragma unroll
  for (int i = 0; i < 24; i++) { F[i][0] = 0; F[i][1] = 0; F[i][2] = 0; }
#pragma unroll
  for (int i = 0; i < 6; i++) gw[i] = 0;

  const float* plane = s_cb + sub*520;
#pragma unroll
  for (int i4 = 0; i4 < 4; i4++) {
    const int n4 = sub*4 + i4;
    float4 v0 = reinterpret_cast<const float4*>(yb)[n4];
    float4 v1 = reinterpret_cast<const float4*>(yb + 64)[n4];
    float4 v2 = reinterpret_cast<const float4*>(yb + 128)[n4];
    float a0[4] = {v0.x, v0.y, v0.z, v0.w};
    float a1[4] = {v1.x, v1.y, v1.z, v1.w};
    float a2[4] = {v2.x, v2.y, v2.z, v2.w};
#pragma unroll
    for (int l = 0; l < 4; l++) {
      const int ni = 4*i4 + l;
      const float4* row = reinterpret_cast<const float4*>(plane + ni*32);
      float4 c0 = row[0];
      float4 ch[6];
#pragma unroll
      for (int cc = 0; cc < 6; cc++) ch[cc] = row[1 + cc];
      const float cb[24] = {ch[0].x, ch[0].y, ch[0].z, ch[0].w,
                            ch[1].x, ch[1].y, ch[1].z, ch[1].w,
                            ch[2].x, ch[2].y, ch[2].z, ch[2].w,
                            ch[3].x, ch[3].y, ch[3].z, ch[3].w,
                            ch[4].x, ch[4].y, ch[4].z, ch[4].w,
                            ch[5].x, ch[5].y, ch[5].z, ch[5].w};
      float ym0 = a0[l], ym1 = a1[l], ym2 = a2[l];
      float wn  = c0.x;
      float wy0 = wn*ym0, wy1 = wn*ym1, wy2 = wn*ym2;
      ywa[0] += wy0; ywa[1] += wy1; ywa[2] += wy2;
      gw[0] += wy0*ym0; gw[1] += wy0*ym1; gw[2] += wy0*ym2;
      gw[3] += wy1*ym1; gw[4] += wy1*ym2; gw[5] += wy2*ym2;
#pragma unroll
      for (int km = 0; km < 24; km++) {
        F[km][0] += cb[km]*ym0; F[km][1] += cb[km]*ym1; F[km][2] += cb[km]*ym2;
      }
    }
  }
  // butterfly partial sums across the 4 subs -> full F, gw, ywa in every lane
#pragma unroll
  for (int km = 0; km < 24; km++)
#pragma unroll
    for (int m = 0; m < 3; m++) {
      float v = F[km][m];
      v += __shfl_xor(v, 1);
      v += __shfl_xor(v, 2);
      F[km][m] = v;
    }
#pragma unroll
  for (int i = 0; i < 6; i++) { float v = gw[i]; v += __shfl_xor(v, 1); v += __shfl_xor(v, 2); gw[i] = v; }
#pragma unroll
  for (int i = 0; i < 3; i++) { float v = ywa[i]; v += __shfl_xor(v, 1); v += __shfl_xor(v, 2); ywa[i] = v; }

  const float iws = 1.0f / wsum;
  float yw[3] = {ywa[0]*iws, ywa[1]*iws, ywa[2]*iws};
  float Gram[6];
  Gram[0] = gw[0] - ywa[0]*ywa[0]*iws;
  Gram[1] = gw[1] - ywa[0]*ywa[1]*iws;
  Gram[2] = gw[2] - ywa[0]*ywa[2]*iws;
  Gram[3] = gw[3] - ywa[1]*ywa[1]*iws;
  Gram[4] = gw[4] - ywa[1]*ywa[2]*iws;
  Gram[5] = gw[5] - ywa[2]*ywa[2]*iws;

  if (sub == 0) s_Q[0][lb] = q00v;
  // q_top: full (redundant x4), distributed writes
#pragma unroll
  for (int e = 0; e < 9; e++) {
    const int j = e / 3, m = e % 3;
    float a = 0;
#pragma unroll
    for (int k = 0; k < 8; k++) a += s_g8[k] * F[k*3 + j][m];
    if ((e & 3) == sub) s_Q[tidx(0, 1 + e)][lb] = -a;
  }
  // own-k slice F6 (static cndmask selects; rows sub*6+kk)
  float F6[6][3];
#pragma unroll
  for (int kk = 0; kk < 6; kk++)
#pragma unroll
    for (int m = 0; m < 3; m++) {
      float x01 = (sub & 1) ? F[6 + kk][m]  : F[kk][m];
      float x23 = (sub & 1) ? F[18 + kk][m] : F[12 + kk][m];
      F6[kk][m] = (sub & 2) ? x23 : x01;
    }
  // FG rows for my k2 in {2sub, 2sub+1} from full F (registers)
  float FGr[2][9];
#pragma unroll
  for (int kk = 0; kk < 2; kk++) {
    float gcol[8];
#pragma unroll
    for (int k = 0; k < 8; k++) {
      float g01 = (sub & 1) ? s_G[k*8 + 2 + kk] : s_G[k*8 + 0 + kk];
      float g23 = (sub & 1) ? s_G[k*8 + 6 + kk] : s_G[k*8 + 4 + kk];
      gcol[k] = (sub & 2) ? g23 : g01;
    }
#pragma unroll
    for (int e = 0; e < 9; e++) {
      const int j = e / 3, m = e % 3;
      float a = 0;
#pragma unroll
      for (int k = 0; k < 8; k++) a += gcol[k] * F[k*3 + j][m];
      FGr[kk][e] = a;
    }
  }
  // q_low: partial over own k2 pair, butterfly, distributed writes
#pragma unroll
  for (int e = 0; e < 9; e++)
#pragma unroll
    for (int f = e; f < 9; f++) {
      const int j = e/3, m = e%3, j2 = f/3, m2 = f%3;
      float p = FGr[0][e] * F6[j2][m2] + FGr[1][e] * F6[3 + j2][m2];
      p += __shfl_xor(p, 1);
      p += __shfl_xor(p, 2);
      if ((tidx(1 + e, 1 + f) & 3) == sub) {
        const float gterm = (j == j2) ? Gram[(m <= m2) ? (m*3 - m*(m+1)/2 + m2) : (m2*3 - m2*(m2+1)/2 + m)] : 0.0f;
        s_Q[tidx(1 + e, 1 + f)][lb] = -2.0f*p + gterm;
      }
    }
  __syncthreads();

  // ---- tridiagonalize Q (register copy) via Householder: T = (ad[10], b2[9]) ----
  float Mm[55];
#pragma unroll
  for (int i = 0; i < 10; i++)
#pragma unroll
    for (int j = 0; j <= i; j++)
      Mm[lidx(i,j)] = s_Q[tidx(j,i)][lb];

  float ad[10], b2[9];
#pragma unroll
  for (int j = 0; j < 8; j++) {
    float s2 = 0;
#pragma unroll
    for (int i = j + 1; i < 10; i++) s2 += Mm[lidx(i,j)] * Mm[lidx(i,j)];
    const float x0 = Mm[lidx(j+1,j)];
    const float anorm = __builtin_amdgcn_sqrtf(s2);
    const float alpha = (x0 > 0.0f) ? -anorm : anorm;
    const float uu = s2 - alpha * x0;
    const float beta = (uu > 1e-35f) ? __builtin_amdgcn_rcpf(uu) : 0.0f;
    float u[10], p[10];
    u[j+1] = x0 - alpha;
#pragma unroll
    for (int i = j + 2; i < 10; i++) u[i] = Mm[lidx(i,j)];
#pragma unroll
    for (int i = j + 1; i < 10; i++) {
      float acc = 0;
#pragma unroll
      for (int k = j + 1; k < 10; k++) acc += Mm[(i >= k) ? lidx(i,k) : lidx(k,i)] * u[k];
      p[i] = beta * acc;
    }
    float K = 0;
#pragma unroll
    for (int i = j + 1; i < 10; i++) K += u[i] * p[i];
    K *= 0.5f * beta;
#pragma unroll
    for (int i = j + 1; i < 10; i++) p[i] -= K * u[i];
#pragma unroll
    for (int i = j + 1; i < 10; i++)
#pragma unroll
      for (int k = j + 1; k <= i; k++)
        Mm[lidx(i,k)] -= u[i]*p[k] + p[i]*u[k];
    ad[j] = Mm[lidx(j,j)];
    b2[j] = s2;
  }
  ad[8] = Mm[lidx(8,8)];
  ad[9] = Mm[lidx(9,9)];
  b2[8] = Mm[lidx(9,8)] * Mm[lidx(9,8)];

  float b2max = b2[0];
#pragma unroll
  for (int i = 1; i < 9; i++) b2max = fmaxf(b2max, b2[i]);
  const float pm = 1e-20f * b2max + 1e-30f;

  // ---- phase A: quaternary Sturm bisection on T (11 rounds == 22 bits) ----
  float lo = 0.0f, hi = s_Q[0][lb];
#pragma unroll
  for (int j = 1; j < 10; j++) hi = fminf(hi, s_Q[tidx(j,j)][lb]);

  const int base = (t & 63) & ~3;
  const float subf = (sub == 0) ? 2.0f : (float)sub;
  for (int round = 0; round < 11; ++round) {
    const float quart = 0.25f * (hi - lo);
    const float mid = lo + quart * subf;
    int neg = 0;
    float d = ad[0] - mid;
    neg += (d < 0.0f) ? 1 : 0;
#pragma unroll
    for (int i = 1; i < 10; i++) {
      d = (fabsf(d) < pm) ? -pm : d;
      d = ad[i] - mid - b2[i-1] * __builtin_amdgcn_rcpf(d);
      neg += (d < 0.0f) ? 1 : 0;
    }
    const int n1 = __shfl(neg, base | 1);
    const int n2 = __shfl(neg, base | 2);
    const int n3 = __shfl(neg, base | 3);
    const float m1 = lo + quart, m2v = lo + 2.0f*quart, m3 = lo + 3.0f*quart;
    const float nlo = (n3 == 0) ? m3 : (n2 == 0) ? m2v : (n1 == 0) ? m1 : lo;
    const float nhi = (n1 > 0) ? m1 : (n2 > 0) ? m2v : (n3 > 0) ? m3 : hi;
    lo = nlo; hi = nhi;
  }

  // ---- phase B: Cholesky of (Q - sigma I) + 3 inverse iterations (redundant x4) ----
  float M[55], id[10];
#pragma unroll
  for (int i = 0; i < 10; i++)
#pragma unroll
    for (int j = 0; j <= i; j++)
      M[lidx(i,j)] = s_Q[tidx(j,i)][lb];
  float tr = 0.0f;
#pragma unroll
  for (int i = 0; i < 10; i++) tr += M[lidx(i,i)];
  const float delta = 1e-5f * fabsf(tr) + 1e-30f;
  const float sigma = lo - delta;
#pragma unroll
  for (int i = 0; i < 10; i++) M[lidx(i,i)] -= sigma;

#pragma unroll
  for (int j = 0; j < 10; j++) {
    float d = M[lidx(j,j)];
#pragma unroll
    for (int t2 = 0; t2 < j; t2++) d -= M[lidx(j,t2)] * M[lidx(j,t2)];
    d = fmaxf(d, 1e-30f);
    float is = __builtin_amdgcn_rsqf(d);
    id[j] = is;
#pragma unroll
    for (int i = j + 1; i < 10; i++) {
      float a = M[lidx(i,j)];
#pragma unroll
      for (int t2 = 0; t2 < j; t2++) a -= M[lidx(i,t2)] * M[lidx(j,t2)];
      M[lidx(i,j)] = a * is;
    }
  }

  float x[10];
#pragma unroll
  for (int i = 0; i < 10; i++) x[i] = 1.0f;
#pragma unroll
  for (int it = 0; it < 3; ++it) {
#pragma unroll
    for (int i = 0; i < 10; i++) {
      float a = x[i];
#pragma unroll
      for (int j = 0; j < i; j++) a -= M[lidx(i,j)] * x[j];
      x[i] = a * id[i];
    }
#pragma unroll
    for (int i = 9; i >= 0; i--) {
      float a = x[i];
#pragma unroll
      for (int j = i + 1; j < 10; j++) a -= M[lidx(j,i)] * x[j];
      x[i] = a * id[i];
    }
    float s2 = 0;
#pragma unroll
    for (int i = 0; i < 10; i++) s2 += x[i]*x[i];
    float sc = __builtin_amdgcn_rsqf(s2 + 1e-38f);
#pragma unroll
    for (int i = 0; i < 10; i++) x[i] *= sc;
  }

  // ---- epilogue: R, c, t ----
  const float inv0 = __builtin_amdgcn_rcpf(x[0]);
  float R[3][3];
#pragma unroll
  for (int r = 0; r < 3; r++)
#pragma unroll
    for (int cc = 0; cc < 3; cc++)
      R[r][cc] = x[1 + 3*cc + r] * inv0;

  float cv[2];
#pragma unroll
  for (int kk = 0; kk < 2; kk++) {
    const int k = sub*2 + kk;
    float a = 0;
#pragma unroll
    for (int e = 0; e < 9; e++) a += x[1 + e] * FGr[kk][e];
    cv[kk] = 2.0f * inv0 * a + s_g8[k];
    out[(size_t)12*Bn + (size_t)b*8 + k] = cv[kk];
  }
  float um0 = s_bw[(sub*2)*3 + 0]*cv[0] + s_bw[(sub*2 + 1)*3 + 0]*cv[1];
  float um1 = s_bw[(sub*2)*3 + 1]*cv[0] + s_bw[(sub*2 + 1)*3 + 1]*cv[1];
  float um2 = s_bw[(sub*2)*3 + 2]*cv[0] + s_bw[(sub*2 + 1)*3 + 2]*cv[1];
  um0 += __shfl_xor(um0, 1); um0 += __shfl_xor(um0, 2);
  um1 += __shfl_xor(um1, 1); um1 += __shfl_xor(um1, 2);
  um2 += __shfl_xor(um2, 1); um2 += __shfl_xor(um2, 2);

#pragma unroll
  for (int r = 0; r < 3; r++)
#pragma unroll
    for (int cc = 0; cc < 3; cc++)
      if (((r*3 + cc) & 3) == sub)
        out[(size_t)b*9 + r*3 + cc] = R[r][cc];
  if (sub == 0) {
#pragma unroll
    for (int r = 0; r < 3; r++)
      out[(size_t)9*Bn + (size_t)b*3 + r] = yw[r] - (R[r][0]*um0 + R[r][1]*um1 + R[r][2]*um2);
  }
}

extern "C" void kernel_launch(void* const* d_in, const int* in_sizes, int n_in,
                              void* d_out, int out_size, void* d_ws, size_t ws_size,
                              hipStream_t stream) {
  const float* y   = (const float*)d_in[0];
  const float* bb  = (const float*)d_in[1];
  const float* w   = (const float*)d_in[2];
  const float* lam = (const float*)d_in[3];
  float* out = (float*)d_out;
  (void)d_ws; (void)ws_size;
  k_main<<<Bn/64, 256, 0, stream>>>(y, bb, w, lam, out);
}